// Round 1
// 84.743 us; speedup vs baseline: 1.0816x; 1.0816x over previous
//
#include <hip/hip_runtime.h>

// Chamfer loss: pred [8,4096,3] f32, gt [8,4096,3] f32 -> scalar f32.
// loss = mean_b[ mean(d1)+mean(d2) + 3*(mean(top2048(d1)) + mean(top2048(d2))) ]
//
// Fixed floor: harness re-poisons the full 256 MB d_ws before every timed
// launch (~40 us fillBuffer @ 6.7 TB/s) — untouchable.
//
// Round-6: budget reconstruction (this=91.7, R4-scalar=98.6 with A~36us)
// puts the 16x16x32-MFMA nn_min at ~29-30 us — ~4x above its throughput
// roofline (~7 us) — i.e. per-iteration issue/latency-bound (256 skinny
// iterations/wave: ds_read lgkm wait + MFMA->v_min hazard dominate).
// Fix: 32x32x16 MFMA = 1024 pairs/inst (4x). Same 268M pairs now need
// 262K MFMAs / 64 fat iterations per wave. Per wave: 32 queries x 2048 g;
// block = 4 waves = 2 q-groups x 2 g-halves sharing one staged g-tile;
// halves merged via tiny LDS buffer. fminf(fminf(a,b),c) written to fuse
// into v_min3_f32. Numerics identical to round-5 (absmax was 0.0).

#define BATCH 8
#define NPTS  4096
#define TOPK  2048
#define BT    256
#define NROW  (2 * BATCH)      // 16 rows = b*2+dir

typedef _Float16 half8 __attribute__((ext_vector_type(8)));
typedef float floatx16 __attribute__((ext_vector_type(16)));

static __device__ inline unsigned pack_h2(float a, float b) {
  unsigned short ua = __builtin_bit_cast(unsigned short, (_Float16)a);
  unsigned short ub = __builtin_bit_cast(unsigned short, (_Float16)b);
  return (unsigned)ua | ((unsigned)ub << 16);
}

// ---------------- Kernel A: min squared distance via 32x32x16 MFMA ---------
// grid (64,16) = 1024 blocks -> 4 blocks/CU, 16 waves/CU, 4 waves/SIMD.
// sqd[q][g] = qn_f32 + (A.B), A=(qx,qy,qz,1) f16 (K=4 of 16), B=(-2gx,-2gy,
// -2gz,gn) f16. Lanes 0-31 carry k=0..7 fragments; lanes 32-63 (k=8..15)
// stream a 32-entry zero region (bank pattern complements data reads ->
// even 4 touches/bank = the wave64-b64 minimum).
__global__ __launch_bounds__(BT, 4) void nn_min_kernel(
    const float* __restrict__ pred, const float* __restrict__ gt,
    float* __restrict__ minsq /* [NROW][NPTS] */, float* __restrict__ out) {
  const int bz  = blockIdx.y;          // b*2 + dir
  const int b   = bz >> 1;
  const int dir = bz & 1;
  const float* q = (dir == 0 ? pred : gt) + (size_t)b * NPTS * 3;
  const float* g = (dir == 0 ? gt : pred) + (size_t)b * NPTS * 3;

  __shared__ uint2 gsh[NPTS + 32];     // f16x4 (-2x,-2y,-2z,|g|^2) + zero slots
  __shared__ float comb[4][2][16];     // per-wave per-half partial minima
  const int tid = threadIdx.x;

  // Stage all 4096 g-points: 4 points/thread/chunk via 3x float4 loads,
  // packed + written as 2x ds_write_b128.
#pragma unroll
  for (int c = 0; c < 4; c++) {
    int p = c * 1024 + tid * 4;                      // 4 consecutive points
    const float4* src = (const float4*)(g + 3 * p);  // 12 floats, 16B-aligned
    float4 f0 = src[0], f1 = src[1], f2 = src[2];
    float x0 = f0.x, y0 = f0.y, z0 = f0.z;
    float x1 = f0.w, y1 = f1.x, z1 = f1.y;
    float x2 = f1.z, y2 = f1.w, z2 = f2.x;
    float x3 = f2.y, y3 = f2.z, z3 = f2.w;
    uint2 u0 = make_uint2(pack_h2(-2.f * x0, -2.f * y0),
                          pack_h2(-2.f * z0, x0 * x0 + y0 * y0 + z0 * z0));
    uint2 u1 = make_uint2(pack_h2(-2.f * x1, -2.f * y1),
                          pack_h2(-2.f * z1, x1 * x1 + y1 * y1 + z1 * z1));
    uint2 u2 = make_uint2(pack_h2(-2.f * x2, -2.f * y2),
                          pack_h2(-2.f * z2, x2 * x2 + y2 * y2 + z2 * z2));
    uint2 u3 = make_uint2(pack_h2(-2.f * x3, -2.f * y3),
                          pack_h2(-2.f * z3, x3 * x3 + y3 * y3 + z3 * z3));
    *(uint4*)&gsh[p]     = make_uint4(u0.x, u0.y, u1.x, u1.y);
    *(uint4*)&gsh[p + 2] = make_uint4(u2.x, u2.y, u3.x, u3.y);
  }
  if (tid < 32) gsh[NPTS + tid] = make_uint2(0u, 0u);
  if (tid == 0 && blockIdx.x == 0 && bz == 0) out[0] = 0.0f;  // select accumulates

  const int lane = tid & 63;
  const int wave = tid >> 6;
  const int col  = lane & 31;          // n (g) index within tile
  const int hi   = lane >> 5;          // k-half / row-half selector
  const int qg   = blockIdx.x * 2 + (wave >> 1);   // q-group of 32
  const int gh   = wave & 1;                       // g-half (2048 pts)
  const int q0   = qg * 32;

  // A fragment: lane l<32 holds A[m=l][k=0..7] = (qx,qy,qz,1,0,0,0,0).
  half8 afrag = {};
  float qnv = 0.0f;
  if (lane < 32) {
    int qi = q0 + lane;
    float qx = q[3 * qi + 0], qy = q[3 * qi + 1], qz = q[3 * qi + 2];
    qnv = qx * qx + qy * qy + qz * qz;
    afrag[0] = (_Float16)qx;
    afrag[1] = (_Float16)qy;
    afrag[2] = (_Float16)qz;
    afrag[3] = (_Float16)1.0f;
  }
  __syncthreads();

  const char* lds = (const char*)gsh;
  int off  = (lane < 32) ? (gh * 16384 + col * 8) : (NPTS * 8 + col * 8);
  int step = (lane < 32) ? 32 * 8 : 0;

  floatx16 macc, zc;
#pragma unroll
  for (int i = 0; i < 16; i++) { macc[i] = 3.0e38f; zc[i] = 0.0f; }

  // 64 g-tiles of 32, processed in pairs -> v_min3 fusion on the accumulate.
#pragma unroll 4
  for (int t = 0; t < 32; t++) {
    uint2 w0 = *(const uint2*)(lds + off);
    uint2 w1 = *(const uint2*)(lds + off + step);
    off += 2 * step;
    union { int4 i; half8 h; } b0, b1;
    b0.i = make_int4((int)w0.x, (int)w0.y, 0, 0);
    b1.i = make_int4((int)w1.x, (int)w1.y, 0, 0);
    floatx16 r0 = __builtin_amdgcn_mfma_f32_32x32x16_f16(afrag, b0.h, zc, 0, 0, 0);
    floatx16 r1 = __builtin_amdgcn_mfma_f32_32x32x16_f16(afrag, b1.h, zc, 0, 0, 0);
#pragma unroll
    for (int i = 0; i < 16; i++)
      macc[i] = fminf(fminf(macc[i], r0[i]), r1[i]);
  }

  // C/D layout: col=lane&31 (g), row=(reg&3)+8*(reg>>2)+4*hi (q).
  // Min across the 32 cols (masks stay within each 32-lane half).
#pragma unroll
  for (int mask = 1; mask < 32; mask <<= 1) {
#pragma unroll
    for (int i = 0; i < 16; i++)
      macc[i] = fminf(macc[i], __shfl_xor(macc[i], mask));
  }

  // Exact fp32 |q|^2 per output row, fetched by in-wave shuffle (all lanes
  // active here; source lanes are always < 32).
  float qnr[16];
#pragma unroll
  for (int r = 0; r < 16; r++)
    qnr[r] = __shfl(qnv, (r & 3) + 8 * (r >> 2) + 4 * hi);

  if (col == 0) {
#pragma unroll
    for (int i = 0; i < 16; i += 4)
      *(float4*)&comb[wave][hi][i] =
          make_float4(macc[i], macc[i + 1], macc[i + 2], macc[i + 3]);
  }
  __syncthreads();

  // Even waves merge the two g-halves of their q-group and store 32 rows.
  if ((wave & 1) == 0 && col == 0) {
    float* dst = minsq + (size_t)bz * NPTS + q0;
#pragma unroll
    for (int rq = 0; rq < 4; rq++) {
      float4 outv;
#pragma unroll
      for (int j = 0; j < 4; j++) {
        int r = rq * 4 + j;
        float v = fminf(comb[wave][hi][r], comb[wave + 1][hi][r]);
        ((float*)&outv)[j] = fmaxf(qnr[r] + v, 0.0f);
      }
      *(float4*)(dst + rq * 8 + hi * 4) = outv;
    }
  }
}

// ---------------- Kernel B: sqrt + mean + exact top-k mean per row,
// then atomicAdd into out (out zeroed by nn_min, prior dispatch) ------------
__global__ __launch_bounds__(BT) void select_kernel(
    const float* __restrict__ minsq, float* __restrict__ out) {
  const int row = blockIdx.x;                // 0..15 = b*2+dir
  const float* src = minsq + (size_t)row * NPTS;
  const int tid = threadIdx.x;

  __shared__ float sf[4];
  __shared__ int   si[4];

  const int PER = NPTS / BT;  // 16 values per thread
  float d[PER];
  float sum_all = 0.0f;
#pragma unroll
  for (int j = 0; j < PER; j++) {
    float v = sqrtf(src[tid + BT * j]);
    d[j] = v;
    sum_all += v;
  }

  // block float sum of sum_all
  {
    float v = sum_all;
    for (int off = 32; off > 0; off >>= 1) v += __shfl_down(v, off);
    if ((tid & 63) == 0) sf[tid >> 6] = v;
    __syncthreads();
    sum_all = sf[0] + sf[1] + sf[2] + sf[3];
    __syncthreads();
  }

  // radix-select the TOPK-th largest value (exact, over float bit patterns)
  unsigned sel = 0u;
  for (int bit = 30; bit >= 0; --bit) {   // sign bit is 0 (nonneg)
    unsigned cand = sel | (1u << bit);
    int c = 0;
#pragma unroll
    for (int j = 0; j < PER; j++) c += (__float_as_uint(d[j]) >= cand) ? 1 : 0;
    for (int off = 32; off > 0; off >>= 1) c += __shfl_down(c, off);
    if ((tid & 63) == 0) si[tid >> 6] = c;
    __syncthreads();
    int total = si[0] + si[1] + si[2] + si[3];
    __syncthreads();
    if (total >= TOPK) sel = cand;
  }

  // sum of strictly-greater values + count
  int cgt = 0;
  float sgt = 0.0f;
#pragma unroll
  for (int j = 0; j < PER; j++) {
    if (__float_as_uint(d[j]) > sel) { cgt++; sgt += d[j]; }
  }
  {
    float v = sgt;
    for (int off = 32; off > 0; off >>= 1) v += __shfl_down(v, off);
    if ((tid & 63) == 0) sf[tid >> 6] = v;
    int c = cgt;
    for (int off = 32; off > 0; off >>= 1) c += __shfl_down(c, off);
    if ((tid & 63) == 0) si[tid >> 6] = c;
    __syncthreads();
    sgt = sf[0] + sf[1] + sf[2] + sf[3];
    cgt = si[0] + si[1] + si[2] + si[3];
  }

  if (tid == 0) {
    float kth = __uint_as_float(sel);
    float topk_sum = sgt + (float)(TOPK - cgt) * kth;  // tie-exact vs lax.top_k
    float rowval = sum_all / (float)NPTS + 3.0f * (topk_sum / (float)TOPK);
    atomicAdd(out, rowval * (1.0f / (float)BATCH));
  }
}

extern "C" void kernel_launch(void* const* d_in, const int* in_sizes, int n_in,
                              void* d_out, int out_size, void* d_ws, size_t ws_size,
                              hipStream_t stream) {
  const float* pred = (const float*)d_in[0];
  const float* gt   = (const float*)d_in[1];
  float* out = (float*)d_out;

  float* minsq = (float*)d_ws;   // [NROW][NPTS] = 256 KB

  dim3 gridA(NPTS / 64, NROW);   // (64,16) = 1024 blocks
  nn_min_kernel<<<gridA, BT, 0, stream>>>(pred, gt, minsq, out);
  select_kernel<<<NROW, BT, 0, stream>>>(minsq, out);
}